// Round 1
// baseline (19910.133 us; speedup 1.0000x reference)
//
#include <hip/hip_runtime.h>
#include <hip/hip_cooperative_groups.h>
#include <cmath>

namespace cg = cooperative_groups;

#define T_STEPS 512
#define EDIM 512
#define HDIM 1024
#define CDIM 512
#define BDIM 128
#define NG 4096  // 4*H, gate-interleaved: col = unit*4 + gate

typedef _Float16 h8 __attribute__((ext_vector_type(8)));
typedef float f4 __attribute__((ext_vector_type(4)));

// ---------------- pack P = emb @ [Wx interleaved] + bias : [513][4096] fp32 (exact input path)
// grid (65, 16), block 256. Each block: 8 emb rows x 256 cols.
__global__ void pack_P(const float* __restrict__ emb,
                       const float* __restrict__ Wgx, const float* __restrict__ Wix,
                       const float* __restrict__ Wfx, const float* __restrict__ Wox,
                       const float* __restrict__ bg, const float* __restrict__ bi,
                       const float* __restrict__ bf_, const float* __restrict__ bo,
                       float* __restrict__ P) {
  __shared__ float es[8][512];
  const int vg = blockIdx.x;   // 0..64
  const int st = blockIdx.y;   // 0..15
  const int tid = threadIdx.x;
  for (int i = tid; i < 8 * 512; i += 256) {
    int vv = i >> 9, k = i & 511;
    int v = vg * 8 + vv;
    es[vv][k] = (v < 513) ? emb[v * 512 + k] : 0.f;
  }
  __syncthreads();
  const int c = st * 256 + tid;         // global gate-interleaved col
  const int gate = c & 3, unit = c >> 2;
  const float* W = gate == 0 ? Wgx : gate == 1 ? Wix : gate == 2 ? Wfx : Wox;
  const float* bias = gate == 0 ? bg : gate == 1 ? bi : gate == 2 ? bf_ : bo;
  float acc[8];
  const float bv = bias[unit];
#pragma unroll
  for (int vv = 0; vv < 8; vv++) acc[vv] = bv;
  for (int k = 0; k < 512; k++) {
    float w = W[k * 1024 + unit];
#pragma unroll
    for (int vv = 0; vv < 8; vv++) acc[vv] += es[vv][k] * w;
  }
#pragma unroll
  for (int vv = 0; vv < 8; vv++) {
    int v = vg * 8 + vv;
    if (v < 513) P[(size_t)v * 4096 + c] = acc[vv];
  }
}

// ---------------- pack Wt[c][k] = W_{gate(c)}h[k][unit(c)] as fp16 (transposed for MFMA B-frags)
// grid 4096, block 256
__global__ void pack_Wt(const float* __restrict__ Wgh, const float* __restrict__ Wih,
                        const float* __restrict__ Wfh, const float* __restrict__ Woh,
                        _Float16* __restrict__ Wt) {
  const int c = blockIdx.x;
  const int gate = c & 3, unit = c >> 2;
  const float* W = gate == 0 ? Wgh : gate == 1 ? Wih : gate == 2 ? Wfh : Woh;
  for (int k = threadIdx.x; k < 1024; k += 256)
    Wt[(size_t)c * 1024 + k] = (_Float16)W[k * 1024 + unit];
}

// ---------------- persistent LSTM: 128 blocks x 512 threads, 1 grid.sync per step
// Block b owns output cols [32b, 32b+32) = hidden units [8b, 8b+8) x 4 gates.
// Wave w (0..7) computes rows [16w,16w+16) x 32 cols via 2 MFMA tiles, K=1024 fp16.
__launch_bounds__(512)
__global__ void lstm_step_all(const int* __restrict__ x,
                              const float* __restrict__ P,
                              const _Float16* __restrict__ Wt,
                              _Float16* __restrict__ hbuf,
                              float* __restrict__ h32,
                              const float* __restrict__ h_init,
                              const float* __restrict__ c_init) {
  cg::grid_group grid = cg::this_grid();
  __shared__ float pre[128][33];
  __shared__ float cst[128][8];
  __shared__ int xs[128];
  const int tid = threadIdx.x;
  const int blk = blockIdx.x;  // 0..127
  const int lane = tid & 63;
  const int wid = tid >> 6;    // 0..7
  const int colbase = blk * 32;

  // init h_buf[0] (fp16) and block-local c state
#pragma unroll
  for (int rep = 0; rep < 2; rep++) {
    int pidx = tid + 512 * rep;
    int row = pidx >> 3, u = pidx & 7;
    int ug = blk * 8 + u;
    hbuf[row * 1024 + ug] = (_Float16)h_init[ug];
    cst[row][u] = c_init[ug];
  }
  grid.sync();

  const int l15 = lane & 15;
  const int kgrp = (lane >> 4) * 8;  // k offset inside 32-chunk
  const int arow = wid * 16 + l15;   // A row this lane loads
  const int bcol0 = colbase + l15;
  const int bcol1 = bcol0 + 16;

  for (int t = 0; t < T_STEPS; t++) {
    const _Float16* hc = hbuf + (t & 1) * (128 * 1024);
    _Float16* hn = hbuf + ((t + 1) & 1) * (128 * 1024);
    if (tid < 128) xs[tid] = x[tid * 513 + t];
    __syncthreads();

    // acc init = exact fp32 input-path pre-activation gathered from P
    f4 acc0, acc1;
#pragma unroll
    for (int r = 0; r < 4; r++) {
      int row = wid * 16 + (lane >> 4) * 4 + r;
      const float* prow = P + (size_t)xs[row] * 4096;
      acc0[r] = prow[bcol0];
      acc1[r] = prow[bcol1];
    }

    // recurrent GEMM: [128 x 1024] x [1024 x 4096], this wave: 16 rows x 32 cols
    const _Float16* ap = hc + arow * 1024 + kgrp;
    const _Float16* bp0 = Wt + (size_t)bcol0 * 1024 + kgrp;
    const _Float16* bp1 = Wt + (size_t)bcol1 * 1024 + kgrp;
#pragma unroll 4
    for (int k0 = 0; k0 < 1024; k0 += 32) {
      h8 a = *(const h8*)(ap + k0);
      h8 b0 = *(const h8*)(bp0 + k0);
      h8 b1 = *(const h8*)(bp1 + k0);
      acc0 = __builtin_amdgcn_mfma_f32_16x16x32_f16(a, b0, acc0, 0, 0, 0);
      acc1 = __builtin_amdgcn_mfma_f32_16x16x32_f16(a, b1, acc1, 0, 0, 0);
    }

    // scatter pre-activations to LDS
#pragma unroll
    for (int r = 0; r < 4; r++) {
      int row = wid * 16 + (lane >> 4) * 4 + r;
      pre[row][l15] = acc0[r];
      pre[row][l15 + 16] = acc1[r];
    }
    __syncthreads();

    // gate nonlinearity + state update (block-local c, 8 units x 128 rows)
#pragma unroll
    for (int rep = 0; rep < 2; rep++) {
      int pidx = tid + 512 * rep;
      int row = pidx >> 3, u = pidx & 7;
      float g = tanhf(pre[row][u * 4 + 0]);
      float i = 1.f / (1.f + expf(-pre[row][u * 4 + 1]));
      float f = 1.f / (1.f + expf(-pre[row][u * 4 + 2]));
      float o = 1.f / (1.f + expf(-pre[row][u * 4 + 3]));
      float cn = g * i + cst[row][u] * f;
      cst[row][u] = cn;
      float hv = tanhf(cn) * o;
      int ug = blk * 8 + u;
      hn[row * 1024 + ug] = (_Float16)hv;
      if (t == T_STEPS - 1) h32[row * 1024 + ug] = hv;
    }
    grid.sync();
  }
}

// ---------------- final projection p = h_T @ W_ph + b_p (fp32)
__global__ void proj(const float* __restrict__ h32, const float* __restrict__ Wph,
                     const float* __restrict__ bp, float* __restrict__ logits) {
  const int b = blockIdx.x >> 1;
  const int cc = (blockIdx.x & 1) * 256 + threadIdx.x;
  const float* hrow = h32 + b * 1024;
  float acc = bp[cc];
#pragma unroll 4
  for (int k = 0; k < 1024; k++) acc += hrow[k] * Wph[k * 512 + cc];
  logits[b * 512 + cc] = acc;
}

// ---------------- row-wise log_softmax, 1 block per row
__global__ void lsm(const float* __restrict__ logits, float* __restrict__ out) {
  const int b = blockIdx.x;
  const int tid = threadIdx.x;
  __shared__ float sm[4];
  __shared__ float se[4];
  float v0 = logits[b * 512 + tid];
  float v1 = logits[b * 512 + 256 + tid];
  float m = fmaxf(v0, v1);
  for (int o = 1; o < 64; o <<= 1) m = fmaxf(m, __shfl_xor(m, o, 64));
  if ((tid & 63) == 0) sm[tid >> 6] = m;
  __syncthreads();
  m = fmaxf(fmaxf(sm[0], sm[1]), fmaxf(sm[2], sm[3]));
  float e = expf(v0 - m) + expf(v1 - m);
  for (int o = 1; o < 64; o <<= 1) e += __shfl_xor(e, o, 64);
  if ((tid & 63) == 0) se[tid >> 6] = e;
  __syncthreads();
  float ls = logf(se[0] + se[1] + se[2] + se[3]) + m;
  out[b * 512 + tid] = v0 - ls;
  out[b * 512 + 256 + tid] = v1 - ls;
}

extern "C" void kernel_launch(void* const* d_in, const int* in_sizes, int n_in,
                              void* d_out, int out_size, void* d_ws, size_t ws_size,
                              hipStream_t stream) {
  const int* x = (const int*)d_in[0];
  const float* emb = (const float*)d_in[1];
  const float* Wgx = (const float*)d_in[2];
  const float* Wgh = (const float*)d_in[3];
  const float* bg = (const float*)d_in[4];
  const float* Wix = (const float*)d_in[5];
  const float* Wih = (const float*)d_in[6];
  const float* bi = (const float*)d_in[7];
  const float* Wfx = (const float*)d_in[8];
  const float* Wfh = (const float*)d_in[9];
  const float* bf = (const float*)d_in[10];
  const float* Wox = (const float*)d_in[11];
  const float* Woh = (const float*)d_in[12];
  const float* bo = (const float*)d_in[13];
  const float* Wph = (const float*)d_in[14];
  const float* bp = (const float*)d_in[15];
  const float* h_init = (const float*)d_in[16];
  const float* c_init = (const float*)d_in[17];

  char* ws = (char*)d_ws;
  float* P = (float*)ws;                                   // 520*4096*4   = 8,519,680
  _Float16* Wt = (_Float16*)(ws + 8519680);                // 4096*1024*2  = 8,388,608
  _Float16* hbuf = (_Float16*)(ws + 8519680 + 8388608);    // 2*128*1024*2 = 524,288
  float* h32 = (float*)(ws + 8519680 + 8388608 + 524288);  // 128*1024*4   = 524,288
  float* logits = (float*)(ws + 8519680 + 8388608 + 524288 + 524288);  // 128*512*4

  pack_P<<<dim3(65, 16), 256, 0, stream>>>(emb, Wgx, Wix, Wfx, Wox, bg, bi, bf, bo, P);
  pack_Wt<<<4096, 256, 0, stream>>>(Wgh, Wih, Wfh, Woh, Wt);

  void* args[] = {(void*)&x, (void*)&P, (void*)&Wt, (void*)&hbuf,
                  (void*)&h32, (void*)&h_init, (void*)&c_init};
  hipLaunchCooperativeKernel((void*)lstm_step_all, dim3(128), dim3(512), args, 0, stream);

  proj<<<256, 256, 0, stream>>>(h32, Wph, bp, logits);
  lsm<<<128, 256, 0, stream>>>(logits, (float*)d_out);
}

// Round 2
// 7274.361 us; speedup vs baseline: 2.7370x; 2.7370x over previous
//
#include <hip/hip_runtime.h>
#include <hip/hip_cooperative_groups.h>
#include <cmath>

namespace cg = cooperative_groups;

#define T_STEPS 512
#define NBLK 128
#define FLAG_STRIDE 16  // 64B-padded flag slots

typedef _Float16 h8 __attribute__((ext_vector_type(8)));
typedef float f4 __attribute__((ext_vector_type(4)));

// ---------------- pack P = emb @ [Wx interleaved] + bias : [513][4096] fp32 (exact input path)
__global__ void pack_P(const float* __restrict__ emb,
                       const float* __restrict__ Wgx, const float* __restrict__ Wix,
                       const float* __restrict__ Wfx, const float* __restrict__ Wox,
                       const float* __restrict__ bg, const float* __restrict__ bi,
                       const float* __restrict__ bf_, const float* __restrict__ bo,
                       float* __restrict__ P) {
  __shared__ float es[8][512];
  const int vg = blockIdx.x;   // 0..64
  const int st = blockIdx.y;   // 0..15
  const int tid = threadIdx.x;
  for (int i = tid; i < 8 * 512; i += 256) {
    int vv = i >> 9, k = i & 511;
    int v = vg * 8 + vv;
    es[vv][k] = (v < 513) ? emb[v * 512 + k] : 0.f;
  }
  __syncthreads();
  const int c = st * 256 + tid;
  const int gate = c & 3, unit = c >> 2;
  const float* W = gate == 0 ? Wgx : gate == 1 ? Wix : gate == 2 ? Wfx : Wox;
  const float* bias = gate == 0 ? bg : gate == 1 ? bi : gate == 2 ? bf_ : bo;
  float acc[8];
  const float bv = bias[unit];
#pragma unroll
  for (int vv = 0; vv < 8; vv++) acc[vv] = bv;
  for (int k = 0; k < 512; k++) {
    float w = W[k * 1024 + unit];
#pragma unroll
    for (int vv = 0; vv < 8; vv++) acc[vv] += es[vv][k] * w;
  }
#pragma unroll
  for (int vv = 0; vv < 8; vv++) {
    int v = vg * 8 + vv;
    if (v < 513) P[(size_t)v * 4096 + c] = acc[vv];
  }
}

// ---------------- pack Wt[c][k] = W_{gate(c)}h[k][unit(c)] as fp16
__global__ void pack_Wt(const float* __restrict__ Wgh, const float* __restrict__ Wih,
                        const float* __restrict__ Wfh, const float* __restrict__ Woh,
                        _Float16* __restrict__ Wt) {
  const int c = blockIdx.x;
  const int gate = c & 3, unit = c >> 2;
  const float* W = gate == 0 ? Wgh : gate == 1 ? Wih : gate == 2 ? Wfh : Woh;
  for (int k = threadIdx.x; k < 1024; k += 256)
    Wt[(size_t)c * 1024 + k] = (_Float16)W[k * 1024 + unit];
}

// ---------------- persistent LSTM: 128 blocks x 512 threads, custom flag barrier per step
__launch_bounds__(512)
__global__ void lstm_step_all(const int* __restrict__ x,
                              const float* __restrict__ P,
                              const _Float16* __restrict__ Wt,
                              _Float16* __restrict__ hbuf,
                              float* __restrict__ h32,
                              const float* __restrict__ h_init,
                              const float* __restrict__ c_init,
                              unsigned int* __restrict__ flags) {
  cg::grid_group grid = cg::this_grid();
  __shared__ _Float16 wlds[32][1032];  // 66 KB, +8 fp16 row pad (16B, keeps b128 alignment)
  __shared__ float pre[128][36];       // 18.4 KB, 36 keeps 16B alignment for f4 reads
  __shared__ int xs[128];
  const int tid = threadIdx.x;
  const int blk = blockIdx.x;
  const int lane = tid & 63;
  const int wid = tid >> 6;
  const int colbase = blk * 32;

  // reset my flag (graph replays must be deterministic)
  if (tid == 0)
    __hip_atomic_store(&flags[blk * FLAG_STRIDE], 0u, __ATOMIC_RELAXED, __HIP_MEMORY_SCOPE_AGENT);

  // stage time-invariant B slice (32 cols x 1024 k) into LDS
  for (int i = tid; i < 32 * 128; i += 512) {
    int c = i >> 7, ch = i & 127;
    *(h8*)&wlds[c][ch * 8] = *(const h8*)&Wt[(size_t)(colbase + c) * 1024 + ch * 8];
  }

  // per-thread persistent c state: thread owns (row=tid>>2, units 2*(tid&3)+{0,1})
  const int urow = tid >> 2;
  const int upair = tid & 3;
  const int ug0 = blk * 8 + upair * 2;
  float c0 = c_init[ug0], c1 = c_init[ug0 + 1];
  {
    union { _Float16 h[2]; unsigned int u; } pk;
    pk.h[0] = (_Float16)h_init[ug0];
    pk.h[1] = (_Float16)h_init[ug0 + 1];
    *(unsigned int*)&hbuf[urow * 1024 + ug0] = pk.u;  // buffer 0
  }
  grid.sync();  // once: full fences cover h-init, wlds, flag reset

  const int l15 = lane & 15;
  const int kg = (lane >> 4) * 8;
  const int arow = wid * 16 + l15;

  for (int t = 0; t < T_STEPS; t++) {
    const _Float16* hc = hbuf + (t & 1) * (128 * 1024);
    _Float16* hn = hbuf + ((t + 1) & 1) * (128 * 1024);
    int xsr = 0;
    if (tid < 128) xsr = x[tid * 513 + t];  // issued early, used after barrier

    // recurrent GEMM: wave computes 16 rows x 32 cols, K=1024
    f4 acc0 = {0.f, 0.f, 0.f, 0.f}, acc1 = {0.f, 0.f, 0.f, 0.f};
    const _Float16* ap = hc + arow * 1024 + kg;
#pragma unroll 8
    for (int k0 = 0; k0 < 1024; k0 += 32) {
      h8 a = *(const h8*)(ap + k0);
      h8 b0 = *(const h8*)&wlds[l15][kg + k0];
      h8 b1 = *(const h8*)&wlds[l15 + 16][kg + k0];
      acc0 = __builtin_amdgcn_mfma_f32_16x16x32_f16(a, b0, acc0, 0, 0, 0);
      acc1 = __builtin_amdgcn_mfma_f32_16x16x32_f16(a, b1, acc1, 0, 0, 0);
    }

#pragma unroll
    for (int r = 0; r < 4; r++) {
      int row = wid * 16 + (lane >> 4) * 4 + r;
      pre[row][l15] = acc0[r];
      pre[row][l15 + 16] = acc1[r];
    }
    if (tid < 128) xs[tid] = xsr;
    __syncthreads();

    // gate nonlinearity + state update: exact fp32 input path added here
    {
      int xrow = xs[urow];
      const float* prow = P + (size_t)xrow * 4096 + colbase + upair * 8;
      f4 pv0 = *(const f4*)(prow);
      f4 pv1 = *(const f4*)(prow + 4);
      f4 q0 = *(const f4*)&pre[urow][upair * 8];
      f4 q1 = *(const f4*)&pre[urow][upair * 8 + 4];
      float g0 = tanhf(pv0[0] + q0[0]);
      float i0 = 1.f / (1.f + expf(-(pv0[1] + q0[1])));
      float f0 = 1.f / (1.f + expf(-(pv0[2] + q0[2])));
      float o0 = 1.f / (1.f + expf(-(pv0[3] + q0[3])));
      float g1 = tanhf(pv1[0] + q1[0]);
      float i1 = 1.f / (1.f + expf(-(pv1[1] + q1[1])));
      float f1 = 1.f / (1.f + expf(-(pv1[2] + q1[2])));
      float o1 = 1.f / (1.f + expf(-(pv1[3] + q1[3])));
      c0 = g0 * i0 + c0 * f0;
      c1 = g1 * i1 + c1 * f1;
      float hv0 = tanhf(c0) * o0;
      float hv1 = tanhf(c1) * o1;
      union { _Float16 h[2]; unsigned int u; } pk;
      pk.h[0] = (_Float16)hv0;
      pk.h[1] = (_Float16)hv1;
      *(unsigned int*)&hn[urow * 1024 + ug0] = pk.u;
      if (t == T_STEPS - 1) {
        h32[urow * 1024 + ug0] = hv0;
        h32[urow * 1024 + ug0 + 1] = hv1;
      }
    }
    __syncthreads();  // drains all waves' hn stores (vmcnt(0) before s_barrier)

    // release: flush L2 -> L3, publish step
    if (tid == 0) {
      __builtin_amdgcn_fence(__ATOMIC_RELEASE, "agent");
      __hip_atomic_store(&flags[blk * FLAG_STRIDE], (unsigned int)(t + 1),
                         __ATOMIC_RELAXED, __HIP_MEMORY_SCOPE_AGENT);
    }
    // acquire: wait all 128 producers, then invalidate stale cache lines
    if (tid < 128) {
      while (__hip_atomic_load(&flags[tid * FLAG_STRIDE], __ATOMIC_RELAXED,
                               __HIP_MEMORY_SCOPE_AGENT) < (unsigned int)(t + 1)) {
        __builtin_amdgcn_s_sleep(1);
      }
    }
    __syncthreads();
    if (wid == 0) __builtin_amdgcn_fence(__ATOMIC_ACQUIRE, "agent");
    __syncthreads();
  }
}

// ---------------- final projection p = h_T @ W_ph + b_p (fp32)
__global__ void proj(const float* __restrict__ h32, const float* __restrict__ Wph,
                     const float* __restrict__ bp, float* __restrict__ logits) {
  const int b = blockIdx.x >> 1;
  const int cc = (blockIdx.x & 1) * 256 + threadIdx.x;
  const float* hrow = h32 + b * 1024;
  float acc = bp[cc];
#pragma unroll 4
  for (int k = 0; k < 1024; k++) acc += hrow[k] * Wph[k * 512 + cc];
  logits[b * 512 + cc] = acc;
}

// ---------------- row-wise log_softmax
__global__ void lsm(const float* __restrict__ logits, float* __restrict__ out) {
  const int b = blockIdx.x;
  const int tid = threadIdx.x;
  __shared__ float sm[4];
  __shared__ float se[4];
  float v0 = logits[b * 512 + tid];
  float v1 = logits[b * 512 + 256 + tid];
  float m = fmaxf(v0, v1);
  for (int o = 1; o < 64; o <<= 1) m = fmaxf(m, __shfl_xor(m, o, 64));
  if ((tid & 63) == 0) sm[tid >> 6] = m;
  __syncthreads();
  m = fmaxf(fmaxf(sm[0], sm[1]), fmaxf(sm[2], sm[3]));
  float e = expf(v0 - m) + expf(v1 - m);
  for (int o = 1; o < 64; o <<= 1) e += __shfl_xor(e, o, 64);
  if ((tid & 63) == 0) se[tid >> 6] = e;
  __syncthreads();
  float ls = logf(se[0] + se[1] + se[2] + se[3]) + m;
  out[b * 512 + tid] = v0 - ls;
  out[b * 512 + 256 + tid] = v1 - ls;
}

extern "C" void kernel_launch(void* const* d_in, const int* in_sizes, int n_in,
                              void* d_out, int out_size, void* d_ws, size_t ws_size,
                              hipStream_t stream) {
  const int* x = (const int*)d_in[0];
  const float* emb = (const float*)d_in[1];
  const float* Wgx = (const float*)d_in[2];
  const float* Wgh = (const float*)d_in[3];
  const float* bg = (const float*)d_in[4];
  const float* Wix = (const float*)d_in[5];
  const float* Wih = (const float*)d_in[6];
  const float* bi = (const float*)d_in[7];
  const float* Wfx = (const float*)d_in[8];
  const float* Wfh = (const float*)d_in[9];
  const float* bf = (const float*)d_in[10];
  const float* Wox = (const float*)d_in[11];
  const float* Woh = (const float*)d_in[12];
  const float* bo = (const float*)d_in[13];
  const float* Wph = (const float*)d_in[14];
  const float* bp = (const float*)d_in[15];
  const float* h_init = (const float*)d_in[16];
  const float* c_init = (const float*)d_in[17];

  char* ws = (char*)d_ws;
  float* P = (float*)ws;                                   // 520*4096*4   = 8,519,680
  // flags live in P's unused pad rows (rows 513..519 never written by pack_P)
  unsigned int* flags = (unsigned int*)(ws + (size_t)513 * 4096 * 4);  // 8 KB
  _Float16* Wt = (_Float16*)(ws + 8519680);                // 4096*1024*2  = 8,388,608
  _Float16* hbuf = (_Float16*)(ws + 8519680 + 8388608);    // 2*128*1024*2 = 524,288
  float* h32 = (float*)(ws + 8519680 + 8388608 + 524288);  // 128*1024*4   = 524,288
  float* logits = (float*)(ws + 8519680 + 8388608 + 524288 + 524288);  // 128*512*4

  pack_P<<<dim3(65, 16), 256, 0, stream>>>(emb, Wgx, Wix, Wfx, Wox, bg, bi, bf, bo, P);
  pack_Wt<<<4096, 256, 0, stream>>>(Wgh, Wih, Wfh, Woh, Wt);

  void* args[] = {(void*)&x, (void*)&P, (void*)&Wt, (void*)&hbuf,
                  (void*)&h32, (void*)&h_init, (void*)&c_init, (void*)&flags};
  hipLaunchCooperativeKernel((void*)lstm_step_all, dim3(NBLK), dim3(512), args, 0, stream);

  proj<<<256, 256, 0, stream>>>(h32, Wph, bp, logits);
  lsm<<<128, 256, 0, stream>>>(logits, (float*)d_out);
}